// Round 1
// baseline (244.322 us; speedup 1.0000x reference)
//
#include <hip/hip_runtime.h>
#include <stdint.h>

#define N_ANCH 262144
#define NUM_CLASSES 80
#define DET_DIM 84
#define TOP_K 1000
#define MAX_BOXES 300
#define NMS_THR 0.4f

// ---- workspace layout (bytes) ----
#define OFF_KEYS   0u
#define OFF_HIST1  (N_ANCH * 4u)             // 4096 u32
#define OFF_HIST2  (OFF_HIST1 + 16384u)      // 4096 u32
#define OFF_HIST3  (OFF_HIST2 + 16384u)      // 256 u32 (1 KiB slot)
#define OFF_STATE  (OFF_HIST3 + 1024u)       // 16 u32: 0:d1 1:k1 2:pre24 3:k2 4:T 5:r 6:cntA 7:cntB
#define OFF_LISTA  (OFF_STATE + 64u)         // 1024 u32
#define OFF_LISTB  (OFF_LISTA + 4096u)       // 4096 u32
#define OFF_TOPK   (OFF_LISTB + 16384u)      // 1024 u32
#define OFF_BOXK   (OFF_TOPK + 4096u)        // 1024 float4
#define OFF_MASK   (OFF_BOXK + 16384u)       // 1024 rows x 16 u64
#define OFF_SEL    (OFF_MASK + 131072u)      // 304 u32

// Zero hist1+hist2+hist3(+pad)+state contiguously: 16384+16384+1024+64 bytes
#define ZERO_WORDS ((16384u + 16384u + 1024u + 64u) / 4u)

__global__ __launch_bounds__(256) void k_init(uint32_t* __restrict__ z) {
    uint32_t tid = blockIdx.x * 256u + threadIdx.x;
    if (tid < ZERO_WORDS) z[tid] = 0u;
}

// scores = max over 80 classes; key = float bits (all scores >= 0, monotonic)
__global__ __launch_bounds__(256) void k_scores(const float* __restrict__ cls,
                                                uint32_t* __restrict__ keys,
                                                uint32_t* __restrict__ ghist1) {
    __shared__ uint32_t h[4096];
    for (int i = threadIdx.x; i < 4096; i += 256) h[i] = 0u;
    __syncthreads();
    int stride = gridDim.x * 256;
    for (int a = blockIdx.x * 256 + threadIdx.x; a < N_ANCH; a += stride) {
        const float4* q = (const float4*)(cls + (size_t)a * NUM_CLASSES);
        float m = -1.0f;
#pragma unroll
        for (int t = 0; t < 20; ++t) {
            float4 v = q[t];
            m = fmaxf(m, fmaxf(fmaxf(v.x, v.y), fmaxf(v.z, v.w)));
        }
        uint32_t key = __float_as_uint(m);
        keys[a] = key;
        atomicAdd(&h[key >> 20], 1u);
    }
    __syncthreads();
    for (int i = threadIdx.x; i < 4096; i += 256) {
        uint32_t v = h[i];
        if (v) atomicAdd(&ghist1[i], v);
    }
}

// wave(64-lane) scan of a histogram: find bin d with S(d+1) < k <= S(d), S = suffix sum
// writes d -> out[0], k - S(d+1) -> out[1]  (exactly one lane writes)
__device__ __forceinline__ void wave_scan_hist(const uint32_t* __restrict__ hist,
                                               int nbins, uint32_t k,
                                               uint32_t* __restrict__ out, int lane) {
    int per = nbins >> 6;
    int base = lane * per;
    uint32_t partial = 0;
    for (int b = 0; b < per; ++b) partial += hist[base + b];
    uint32_t si = partial;
#pragma unroll
    for (int off = 1; off < 64; off <<= 1) {
        uint32_t v = __shfl_down(si, off);
        if (lane + off < 64) si += v;
    }
    uint32_t se = si - partial;
    if (se < k && k <= si) {
        uint32_t running = se;
        for (int b = base + per - 1; b >= base; --b) {
            uint32_t hv = hist[b];
            running += hv;
            if (running >= k) {
                out[0] = (uint32_t)b;
                out[1] = k - (running - hv);
                break;
            }
        }
    }
}

// pass 2: every block redoes scan of hist1 (cheap, redundant), then histograms digit2
__global__ __launch_bounds__(256) void k_pass2(const uint32_t* __restrict__ keys,
                                               const uint32_t* __restrict__ ghist1,
                                               uint32_t* __restrict__ ghist2,
                                               uint32_t* __restrict__ state) {
    __shared__ uint32_t sd[2];
    __shared__ uint32_t h[4096];
    if (threadIdx.x < 64) wave_scan_hist(ghist1, 4096, TOP_K, sd, threadIdx.x);
    for (int i = threadIdx.x; i < 4096; i += 256) h[i] = 0u;
    __syncthreads();
    uint32_t d1 = sd[0], k1 = sd[1];
    if (threadIdx.x == 0 && blockIdx.x == 0) { state[0] = d1; state[1] = k1; }
    int stride = gridDim.x * 256;
    for (int a = blockIdx.x * 256 + threadIdx.x; a < N_ANCH; a += stride) {
        uint32_t key = keys[a];
        if ((key >> 20) == d1) atomicAdd(&h[(key >> 8) & 0xFFFu], 1u);
    }
    __syncthreads();
    for (int i = threadIdx.x; i < 4096; i += 256) {
        uint32_t v = h[i];
        if (v) atomicAdd(&ghist2[i], v);
    }
}

// pass 3: scan hist2, histogram final 8-bit digit (few candidates -> global atomics ok)
__global__ __launch_bounds__(256) void k_pass3(const uint32_t* __restrict__ keys,
                                               const uint32_t* __restrict__ ghist2,
                                               uint32_t* __restrict__ ghist3,
                                               uint32_t* __restrict__ state) {
    __shared__ uint32_t sd[2];
    if (threadIdx.x < 64) {
        uint32_t k1 = state[1];
        wave_scan_hist(ghist2, 4096, k1, sd, threadIdx.x);
    }
    __syncthreads();
    uint32_t pre24 = (state[0] << 12) | sd[0];
    uint32_t k2 = sd[1];
    if (threadIdx.x == 0 && blockIdx.x == 0) { state[2] = pre24; state[3] = k2; }
    int stride = gridDim.x * 256;
    for (int a = blockIdx.x * 256 + threadIdx.x; a < N_ANCH; a += stride) {
        uint32_t key = keys[a];
        if ((key >> 8) == pre24) atomicAdd(&ghist3[key & 0xFFu], 1u);
    }
}

// scan hist3 -> exact threshold T; compact indices with key>T (listA) and key==T (listB)
__global__ __launch_bounds__(256) void k_compact(const uint32_t* __restrict__ keys,
                                                 const uint32_t* __restrict__ ghist3,
                                                 uint32_t* __restrict__ state,
                                                 uint32_t* __restrict__ listA,
                                                 uint32_t* __restrict__ listB) {
    __shared__ uint32_t sd[2];
    if (threadIdx.x < 64) {
        uint32_t k2 = state[3];
        wave_scan_hist(ghist3, 256, k2, sd, threadIdx.x);
    }
    __syncthreads();
    uint32_t T = (state[2] << 8) | sd[0];
    if (threadIdx.x == 0 && blockIdx.x == 0) { state[4] = T; state[5] = sd[1]; }
    int stride = gridDim.x * 256;
    for (int a = blockIdx.x * 256 + threadIdx.x; a < N_ANCH; a += stride) {
        uint32_t key = keys[a];
        if (key > T) {
            uint32_t p = atomicAdd(&state[6], 1u);
            if (p < 1024u) listA[p] = (uint32_t)a;
        } else if (key == T) {
            uint32_t p = atomicAdd(&state[7], 1u);
            if (p < 4096u) listB[p] = (uint32_t)a;
        }
    }
}

// single block: sort listA by (key desc, idx asc), sort listB idx asc, build topk[1000],
// gather top-k boxes
__global__ __launch_bounds__(1024) void k_finalize(const uint32_t* __restrict__ keys,
                                                   const uint32_t* __restrict__ state,
                                                   const uint32_t* __restrict__ listA,
                                                   const uint32_t* __restrict__ listB,
                                                   uint32_t* __restrict__ topk,
                                                   const float4* __restrict__ boxes,
                                                   float4* __restrict__ boxk) {
    __shared__ unsigned long long A[1024];
    __shared__ uint32_t Bv[4096];
    __shared__ uint32_t tk[1000];
    int t = threadIdx.x;
    uint32_t cntA = state[6]; if (cntA > 999u) cntA = 999u;
    uint32_t cntB = state[7]; if (cntB > 4096u) cntB = 4096u;
    uint32_t r = TOP_K - cntA;

    unsigned long long wv = ~0ull;
    if (t < (int)cntA) {
        uint32_t idx = listA[t];
        uint32_t key = keys[idx];
        wv = ((unsigned long long)(key ^ 0xFFFFFFFFu) << 32) | (unsigned long long)idx;
    }
    A[t] = wv;
    __syncthreads();
    unsigned n2 = 1; while (n2 < cntA) n2 <<= 1;
    for (unsigned k = 2; k <= n2; k <<= 1) {
        for (unsigned j = k >> 1; j > 0; j >>= 1) {
            unsigned i = (unsigned)t;
            unsigned ixj = i ^ j;
            if (i < n2 && ixj > i) {
                unsigned long long a = A[i], b = A[ixj];
                bool up = ((i & k) == 0);
                if (up ? (a > b) : (a < b)) { A[i] = b; A[ixj] = a; }
            }
            __syncthreads();
        }
    }
    if (t < (int)cntA) tk[t] = (uint32_t)(A[t] & 0xFFFFFFFFull);

    unsigned n2b = 1; while (n2b < cntB) n2b <<= 1;
    for (unsigned i = (unsigned)t; i < n2b; i += 1024) Bv[i] = (i < cntB) ? listB[i] : 0xFFFFFFFFu;
    __syncthreads();
    for (unsigned k = 2; k <= n2b; k <<= 1) {
        for (unsigned j = k >> 1; j > 0; j >>= 1) {
            for (unsigned i = (unsigned)t; i < n2b; i += 1024) {
                unsigned ixj = i ^ j;
                if (ixj > i) {
                    uint32_t a = Bv[i], b = Bv[ixj];
                    bool up = ((i & k) == 0);
                    if (up ? (a > b) : (a < b)) { Bv[i] = b; Bv[ixj] = a; }
                }
            }
            __syncthreads();
        }
    }
    if (t < (int)r) tk[cntA + t] = Bv[t];
    __syncthreads();
    if (t < 1000) {
        uint32_t idx = tk[t];
        topk[t] = idx;
        boxk[t] = boxes[idx];
    }
}

// mask[i][w] bit b: box j=64w+b is suppressed by box i (iou>thr && j>i), rows>=1000 zero
__global__ __launch_bounds__(256) void k_mask(const float4* __restrict__ boxk,
                                              unsigned long long* __restrict__ mask) {
    __shared__ float4 bx[1000];
    for (int i = threadIdx.x; i < 1000; i += 256) bx[i] = boxk[i];
    __syncthreads();
    int i = blockIdx.x;
    if (i >= 1000) {
        if (threadIdx.x < 16) mask[(size_t)i * 16 + threadIdx.x] = 0ull;
        return;
    }
    float4 bi = bx[i];
    float areai = __fmul_rn(__fsub_rn(bi.z, bi.x), __fsub_rn(bi.w, bi.y));
    int lane = threadIdx.x & 63;
    int wave = threadIdx.x >> 6;
#pragma unroll
    for (int rr = 0; rr < 4; ++rr) {
        int j = rr * 256 + threadIdx.x;
        bool bit = false;
        if (j < 1000 && j > i) {
            float4 bj = bx[j];
            float areaj = __fmul_rn(__fsub_rn(bj.z, bj.x), __fsub_rn(bj.w, bj.y));
            float ix1 = fmaxf(bi.x, bj.x);
            float iy1 = fmaxf(bi.y, bj.y);
            float ix2 = fminf(bi.z, bj.z);
            float iy2 = fminf(bi.w, bj.w);
            float iw = fmaxf(__fsub_rn(ix2, ix1), 0.0f);
            float ih = fmaxf(__fsub_rn(iy2, iy1), 0.0f);
            float inter = __fmul_rn(iw, ih);
            float uni = __fsub_rn(__fadd_rn(areai, areaj), inter);
            float den = fmaxf(uni, 1e-8f);
            float iou = inter / den;   // IEEE RN (default hipcc fp32 correctly-rounded div)
            bit = iou > NMS_THR;
        }
        unsigned long long bal = __ballot(bit);
        if (lane == 0) mask[(size_t)i * 16 + (rr * 4 + wave)] = bal;
    }
}

// single-wave greedy scan over the bitmask, chunked by 64; early exit at 300 kept
__global__ __launch_bounds__(64) void k_nms(const unsigned long long* __restrict__ mask,
                                            const uint32_t* __restrict__ topk,
                                            uint32_t* __restrict__ sel) {
    __shared__ uint32_t keptList[384];
    int lane = threadIdx.x;
    uint32_t keptCount = 0;
    for (int c = 0; c < 16; ++c) {
        unsigned long long acc = 0ull;
        for (uint32_t s = (uint32_t)lane; s < keptCount; s += 64u)
            acc |= mask[(size_t)keptList[s] * 16 + c];
#pragma unroll
        for (int off = 1; off < 64; off <<= 1) acc |= __shfl_xor(acc, off);
        unsigned long long supp = acc;
        unsigned long long row = mask[(size_t)(c * 64 + lane) * 16 + c];
        for (int i = 0; i < 64; ++i) {
            unsigned long long ri = __shfl(row, i);
            if (!((supp >> i) & 1ull)) supp |= ri;
        }
        unsigned long long validm = (c == 15) ? ((1ull << 40) - 1ull) : ~0ull;
        unsigned long long kept = (~supp) & validm;
        uint32_t cnt = (uint32_t)__popcll(kept);
        if ((kept >> lane) & 1ull) {
            uint32_t pos = keptCount + (uint32_t)__popcll(kept & ((1ull << lane) - 1ull));
            if (pos < 384u) keptList[pos] = (uint32_t)(c * 64 + lane);
        }
        keptCount += cnt;
        __syncthreads();
        if (keptCount >= MAX_BOXES) break;
    }
    for (uint32_t m = (uint32_t)lane; m < MAX_BOXES; m += 64u)
        sel[m] = (m < keptCount) ? topk[keptList[m]] : 0xFFFFFFFFu;
}

__global__ __launch_bounds__(256) void k_out(const uint32_t* __restrict__ sel,
                                             const float* __restrict__ det,
                                             float* __restrict__ out) {
    int tid = blockIdx.x * 256 + threadIdx.x;
    if (tid >= MAX_BOXES * DET_DIM) return;
    int m = tid / DET_DIM;
    int e = tid - m * DET_DIM;
    uint32_t s = sel[m];
    out[tid] = (s == 0xFFFFFFFFu) ? 0.0f : det[(size_t)s * DET_DIM + e];
}

extern "C" void kernel_launch(void* const* d_in, const int* in_sizes, int n_in,
                              void* d_out, int out_size, void* d_ws, size_t ws_size,
                              hipStream_t stream) {
    const float* boxes = (const float*)d_in[0];
    const float* cls   = (const float*)d_in[1];
    const float* det   = (const float*)d_in[2];
    float* out = (float*)d_out;
    char* ws = (char*)d_ws;

    uint32_t* keys  = (uint32_t*)(ws + OFF_KEYS);
    uint32_t* h1    = (uint32_t*)(ws + OFF_HIST1);
    uint32_t* h2    = (uint32_t*)(ws + OFF_HIST2);
    uint32_t* h3    = (uint32_t*)(ws + OFF_HIST3);
    uint32_t* st    = (uint32_t*)(ws + OFF_STATE);
    uint32_t* listA = (uint32_t*)(ws + OFF_LISTA);
    uint32_t* listB = (uint32_t*)(ws + OFF_LISTB);
    uint32_t* topk  = (uint32_t*)(ws + OFF_TOPK);
    float4*   boxk  = (float4*)(ws + OFF_BOXK);
    unsigned long long* mask = (unsigned long long*)(ws + OFF_MASK);
    uint32_t* sel   = (uint32_t*)(ws + OFF_SEL);

    k_init<<<dim3((ZERO_WORDS + 255) / 256), dim3(256), 0, stream>>>(h1);
    k_scores<<<dim3(512), dim3(256), 0, stream>>>(cls, keys, h1);
    k_pass2<<<dim3(256), dim3(256), 0, stream>>>(keys, h1, h2, st);
    k_pass3<<<dim3(256), dim3(256), 0, stream>>>(keys, h2, h3, st);
    k_compact<<<dim3(256), dim3(256), 0, stream>>>(keys, h3, st, listA, listB);
    k_finalize<<<dim3(1), dim3(1024), 0, stream>>>(keys, st, listA, listB, topk,
                                                   (const float4*)boxes, boxk);
    k_mask<<<dim3(1024), dim3(256), 0, stream>>>(boxk, mask);
    k_nms<<<dim3(1), dim3(64), 0, stream>>>(mask, topk, sel);
    k_out<<<dim3((MAX_BOXES * DET_DIM + 255) / 256), dim3(256), 0, stream>>>(sel, det, out);
}